// Round 1
// baseline (26038.599 us; speedup 1.0000x reference)
//
#include <hip/hip_runtime.h>

// ---------------------------------------------------------------------------
// EpisodicMemoryModule, MI355X (gfx950).
// Key insight: softmax over a size-1 axis => attention == 1.0 => the whole
// f_i / l_1 / l_2 branch is dead. Remaining work:
//   Xrh = facts @ recurrent_kernel + bias            (one bf16 MFMA GEMM)
//   3x { 256 sequential GRU steps; memory update }   (persistent kernel,
//        8 clusters x 32 wgs, flag-synced, weights in registers)
// ---------------------------------------------------------------------------

using bf16x8 = __attribute__((ext_vector_type(8))) short;   // 8 bf16 (4 VGPRs)
using fx4    = __attribute__((ext_vector_type(4))) float;

__device__ __forceinline__ unsigned short f2bf(float f) {
  unsigned u = __float_as_uint(f);
  u += 0x7fffu + ((u >> 16) & 1u);          // RNE
  return (unsigned short)(u >> 16);
}
__device__ __forceinline__ float bf2f(unsigned short s) {
  return __uint_as_float(((unsigned)s) << 16);
}

#define MFMA16(a, b, c) __builtin_amdgcn_mfma_f32_16x16x32_bf16((a), (b), (c), 0, 0, 0)

// ---------------- workspace layout (bytes) ----------------
#define WS_XRH   0L                      // [32768][2048] bf16 (rows = n*128+b)
#define WS_FB    134217728L              // [32768][1024] bf16 facts, rows n*128+b
#define WS_BT    201326592L              // [2048][1024] bf16 = recurrent_kernel^T
#define WS_PUB   205520896L              // [2][8][16384] bf16 frag exchange
#define WS_CNT   206045184L              // [8][2048] u32 arrival counters
#define WS_M0    206110720L              // [2][128][1024] f32 memory snapshots
#define WS_TOTAL 207159296L

// ---------------- facts f32 -> bf16, reindex rows to n*128+b ----------------
__global__ void k_facts(const float* __restrict__ facts, short* __restrict__ fb) {
  long i8 = ((long)blockIdx.x * 256 + threadIdx.x) * 8;
  if (i8 >= 33554432L) return;
  int u = (int)(i8 & 1023);
  int bn = (int)(i8 >> 10);       // output row = n*128 + b
  int b = bn & 127, n = bn >> 7;
  const float* src = facts + (((long)b * 256 + n) << 10) + u;
  bf16x8 o;
#pragma unroll
  for (int j = 0; j < 8; ++j) o[j] = (short)f2bf(src[j]);
  *(bf16x8*)(fb + i8) = o;
}

// ---------------- recurrent_kernel (1024,2048) f32 -> Bt (2048,1024) bf16 ----
__global__ void k_trk(const float* __restrict__ rk, short* __restrict__ bt) {
  __shared__ float tile[32][33];
  int j0 = blockIdx.x * 32, k0 = blockIdx.y * 32;
  int tx = threadIdx.x, ty = threadIdx.y;   // (32, 8)
#pragma unroll
  for (int yy = 0; yy < 4; ++yy) {
    int kk = ty + yy * 8;
    tile[kk][tx] = rk[(long)(k0 + kk) * 2048 + j0 + tx];
  }
  __syncthreads();
#pragma unroll
  for (int yy = 0; yy < 4; ++yy) {
    int jj = ty + yy * 8;
    bt[(long)(j0 + jj) * 1024 + k0 + tx] = (short)f2bf(tile[tx][jj]);
  }
}

// ---------------- setup: counters, q->h0 frags, m0[0]=q ----------------
__global__ void k_setup(const float* __restrict__ q, short* __restrict__ pub,
                        unsigned* __restrict__ cnt, float* __restrict__ m0) {
  int t = blockIdx.x * 256 + threadIdx.x;
  int stride = gridDim.x * 256;
  for (int i = t; i < 8 * 2048; i += stride) cnt[i] = ((i & 2047) == 0) ? 32u : 0u;
  // publish q as A-fragments into pub[0]
  for (int i = t; i < 16384; i += stride) {
    int cl = i >> 11, u = i & 2047;
    int kt = u >> 6, ln = u & 63;
    int row = ln & 15, hi = ln >> 4;
    const float* src = q + (long)(cl * 16 + row) * 1024 + kt * 32 + hi * 8;
    bf16x8 o;
#pragma unroll
    for (int j = 0; j < 8; ++j) o[j] = (short)f2bf(src[j]);
    *(bf16x8*)(pub + (long)cl * 16384 + kt * 512 + ln * 8) = o;
  }
  for (int i = t; i < 32768; i += stride)
    ((float4*)m0)[i] = ((const float4*)q)[i];
}

// ---------------- Xrh GEMM: (32768,1024)bf16 @ (1024,2048)bf16 + bias -------
__global__ __launch_bounds__(256) void k_gemm(const short* __restrict__ A,
                                              const short* __restrict__ Bt,
                                              const float* __restrict__ bias,
                                              short* __restrict__ C) {
  __shared__ short As[128 * 40];   // +8 pad breaks bank aliasing
  __shared__ short Bs[128 * 40];
  const int tid = threadIdx.x, lane = tid & 63, wv = tid >> 6;
  const long bm = (long)blockIdx.x * 128;
  const long bn = (long)blockIdx.y * 128;
  fx4 acc[4][4];
#pragma unroll
  for (int m = 0; m < 4; ++m)
#pragma unroll
    for (int n = 0; n < 4; ++n) acc[m][n] = fx4{0.f, 0.f, 0.f, 0.f};
  const int r = tid >> 1, half = tid & 1;
  const short* aSrc = A + (bm + r) * 1024 + half * 16;
  const short* bSrc = Bt + (bn + r) * 1024 + half * 16;
  short* aDst = As + r * 40 + half * 16;
  short* bDst = Bs + r * 40 + half * 16;
  const int wm = (wv & 1) * 64, wn = (wv >> 1) * 64;
  for (int k0 = 0; k0 < 1024; k0 += 32) {
    bf16x8 a0 = *(const bf16x8*)(aSrc + k0);
    bf16x8 a1 = *(const bf16x8*)(aSrc + k0 + 8);
    bf16x8 b0 = *(const bf16x8*)(bSrc + k0);
    bf16x8 b1 = *(const bf16x8*)(bSrc + k0 + 8);
    *(bf16x8*)aDst = a0; *(bf16x8*)(aDst + 8) = a1;
    *(bf16x8*)bDst = b0; *(bf16x8*)(bDst + 8) = b1;
    __syncthreads();
    bf16x8 af[4], bfv[4];
#pragma unroll
    for (int m = 0; m < 4; ++m)
      af[m] = *(const bf16x8*)(As + (wm + m * 16 + (lane & 15)) * 40 + (lane >> 4) * 8);
#pragma unroll
    for (int n = 0; n < 4; ++n)
      bfv[n] = *(const bf16x8*)(Bs + (wn + n * 16 + (lane & 15)) * 40 + (lane >> 4) * 8);
#pragma unroll
    for (int m = 0; m < 4; ++m)
#pragma unroll
      for (int n = 0; n < 4; ++n) acc[m][n] = MFMA16(af[m], bfv[n], acc[m][n]);
    __syncthreads();
  }
#pragma unroll
  for (int n = 0; n < 4; ++n) {
    long colg = bn + wn + n * 16 + (lane & 15);
    float bv = bias[colg];
#pragma unroll
    for (int m = 0; m < 4; ++m) {
      long rowg = bm + wm + m * 16 + (lane >> 4) * 4;
#pragma unroll
      for (int rr = 0; rr < 4; ++rr)
        C[(rowg + rr) * 2048 + colg] = (short)f2bf(acc[m][n][rr] + bv);
    }
  }
}

// ---------------- persistent GRU scan + memory updates ----------------
// 256 wgs x 256 thr. cluster cl = blockIdx&7 (XCD round-robin friendly),
// slot w = blockIdx>>3 owns output cols [w*32, w*32+32) of both GEMVs.
// Per round: gate on cluster counter, all-gather h fragments, 16 MFMAs/wave
// (K split over 4 waves), LDS reduce, activation, publish own frag slice.

#define GATE()                                                                          \
  do {                                                                                  \
    if (tid == 0) {                                                                     \
      while (__hip_atomic_load(cntc + R, __ATOMIC_ACQUIRE, __HIP_MEMORY_SCOPE_AGENT) <  \
             32u)                                                                       \
        __builtin_amdgcn_s_sleep(1);                                                    \
    }                                                                                   \
    __syncthreads();                                                                    \
    __builtin_amdgcn_fence(__ATOMIC_ACQUIRE, "agent");                                  \
  } while (0)

#define ARRIVE()                                                                        \
  do {                                                                                  \
    __syncthreads();                                                                    \
    if (tid == 0)                                                                       \
      __hip_atomic_fetch_add(cntc + R + 1, 1u, __ATOMIC_RELEASE,                        \
                             __HIP_MEMORY_SCOPE_AGENT);                                 \
    ++R;                                                                                \
  } while (0)

#define HALF_STEP(CONSUME, PRODUCE, BW, COLBASE, IS_R)                                  \
  {                                                                                     \
    unsigned xv = *(const unsigned*)(Xrh + xrow + (COLBASE) + c0); /* pre-gate */       \
    GATE();                                                                             \
    fx4 a0 = {0.f, 0.f, 0.f, 0.f}, a1 = {0.f, 0.f, 0.f, 0.f};                           \
    _Pragma("unroll") for (int kk = 0; kk < 8; ++kk) {                                  \
      bf16x8 av = *(const bf16x8*)((CONSUME) + ((wv * 8 + kk) * 512 + lane * 8));       \
      a0 = MFMA16(av, BW[kk][0], a0);                                                   \
      a1 = MFMA16(av, BW[kk][1], a1);                                                   \
    }                                                                                   \
    _Pragma("unroll") for (int rr = 0; rr < 4; ++rr) {                                  \
      scratch[(wv * 2 + 0) * 256 + ((lane >> 4) * 4 + rr) * 16 + (lane & 15)] = a0[rr]; \
      scratch[(wv * 2 + 1) * 256 + ((lane >> 4) * 4 + rr) * 16 + (lane & 15)] = a1[rr]; \
    }                                                                                   \
    __syncthreads();                                                                    \
    {                                                                                   \
      int ct0 = c0 >> 4, cc0 = c0 & 15;                                                 \
      int ct1 = (c0 + 1) >> 4, cc1 = (c0 + 1) & 15;                                     \
      float s0 = scratch[ct0 * 256 + r5 * 16 + cc0] +                                   \
                 scratch[(2 + ct0) * 256 + r5 * 16 + cc0] +                             \
                 scratch[(4 + ct0) * 256 + r5 * 16 + cc0] +                             \
                 scratch[(6 + ct0) * 256 + r5 * 16 + cc0];                              \
      float s1 = scratch[ct1 * 256 + r5 * 16 + cc1] +                                   \
                 scratch[(2 + ct1) * 256 + r5 * 16 + cc1] +                             \
                 scratch[(4 + ct1) * 256 + r5 * 16 + cc1] +                             \
                 scratch[(6 + ct1) * 256 + r5 * 16 + cc1];                              \
      float p0 = s0 + bf2f((unsigned short)(xv & 0xffffu));                             \
      float p1 = s1 + bf2f((unsigned short)(xv >> 16));                                 \
      float v0, v1;                                                                     \
      if (IS_R) {                                                                       \
        float r0 = fminf(fmaxf(0.2f * p0 + 0.5f, 0.f), 1.f);                            \
        float r1 = fminf(fmaxf(0.2f * p1 + 0.5f, 0.f), 1.f);                            \
        v0 = r0 * h0; v1 = r1 * h1;                                                     \
      } else {                                                                          \
        v0 = 1.f / (1.f + __expf(-p0));                                                 \
        v1 = 1.f / (1.f + __expf(-p1));                                                 \
        h0 = v0; h1 = v1;                                                               \
      }                                                                                 \
      *(unsigned*)((PRODUCE) + pubOff) =                                                \
          (unsigned)f2bf(v0) | ((unsigned)f2bf(v1) << 16);                              \
    }                                                                                   \
    ARRIVE();                                                                           \
  }

__global__ __launch_bounds__(256, 1) void k_scan(
    const short* __restrict__ Xrh, const float* __restrict__ rk,
    const float* __restrict__ q, const float* __restrict__ mnet,
    const float* __restrict__ mbias, short* __restrict__ pub,
    unsigned* __restrict__ cnt, float* __restrict__ m0, float* __restrict__ out) {
  __shared__ short wstage[4096];     // 8 KB weight-frag bounce
  __shared__ float scratch[5120];    // 20 KB: scan partials / update cat+acc
  const int tid = threadIdx.x;
  const int lane = tid & 63, wv = tid >> 6;
  const int g = blockIdx.x, cl = g & 7, w = g >> 3;

  // ---- weight B-fragments into registers (wave wv owns k-tiles wv*8..wv*8+7)
  bf16x8 bfrR[8][2], bfrH[8][2];
#pragma unroll
  for (int kind = 0; kind < 2; ++kind) {
#pragma unroll
    for (int ch = 0; ch < 8; ++ch) {
      for (int it = 0; it < 16; ++it) {   // stage 128 k-rows x 32 cols
        int idx = it * 256 + tid;
        int kl = idx >> 5, cc = idx & 31;
        float v = rk[(long)(ch * 128 + kl) * 2048 + kind * 1024 + w * 32 + cc];
        int kt4 = kl >> 5, kr = kl & 31;
        int hi2 = kr >> 3, j = kr & 7;
        int ct = cc >> 4, l15 = cc & 15;
        wstage[((kt4 * 2 + ct) * 64 + (hi2 * 16 + l15)) * 8 + j] = (short)f2bf(v);
      }
      __syncthreads();
      if (wv == (ch >> 1)) {
#pragma unroll
        for (int kt4 = 0; kt4 < 4; ++kt4)
#pragma unroll
          for (int ct = 0; ct < 2; ++ct) {
            bf16x8 fr = *(const bf16x8*)&wstage[((kt4 * 2 + ct) * 64 + lane) * 8];
            if (kind == 0) bfrR[(ch & 1) * 4 + kt4][ct] = fr;
            else           bfrH[(ch & 1) * 4 + kt4][ct] = fr;
          }
      }
      __syncthreads();
    }
  }

  // ---- per-thread output mapping: (row r5, cols c0,c0+1) of this wg's slice
  const int r5 = (tid >> 2) & 15, q2 = tid & 3;
  const int c0 = wv * 8 + q2 * 2;
  const int browg = cl * 16 + r5;
  float h0 = q[(long)browg * 1024 + w * 32 + c0];
  float h1 = q[(long)browg * 1024 + w * 32 + c0 + 1];
  unsigned* cntc = cnt + cl * 2048;
  const int pubOff = w * 512 + (wv * 16 + r5) * 8 + q2 * 2;
  const long clOff = (long)cl * 16384;
  int R = 0;

  for (int s = 0; s < 3; ++s) {
    const int pin = s & 1;
    short* bufH = pub + (long)pin * 131072 + clOff;
    short* bufP = pub + (long)(pin ^ 1) * 131072 + clOff;
    for (int n = 0; n < 256; ++n) {
      const long xrow = ((long)n * 128 + browg) * 2048;
      HALF_STEP(bufH, bufP, bfrR, w * 32, 1)          // r = hsig(Xr + h@k_r); p=r*h
      HALF_STEP(bufP, bufH, bfrH, 1024 + w * 32, 0)   // h' = sig(Xh + p@k_h)
    }
    // ---------- memory update: relu([m0, episode, q] @ mnet + mbias) ----------
    {
      const float* m0r = m0 + (long)(s & 1) * 131072;
      float* m0w = m0 + (long)((s + 1) & 1) * 131072;
      GATE();
      short* catS = (short*)scratch;     // [16][128] bf16
      float* accb = scratch + 1024;      // [8][16][32] f32
      float acc[16];
#pragma unroll
      for (int r2 = 0; r2 < 16; ++r2) acc[r2] = 0.f;
      const int cc2 = tid & 31, ig = tid >> 5;
      const int cg = w * 32 + cc2;
      const int rowst = tid >> 4, ioff = (tid & 15) * 8;
      for (int ib = 0; ib < 24; ++ib) {
        int ibase = ib * 128 + ioff;
        bf16x8 vals;
        if (ib < 8) {
          const float* src = m0r + (long)(cl * 16 + rowst) * 1024 + ibase;
#pragma unroll
          for (int j = 0; j < 8; ++j) vals[j] = (short)f2bf(src[j]);
        } else if (ib < 16) {
          int col8 = ibase - 1024;
          int kt = col8 >> 5, hi3 = (col8 >> 3) & 3;
          vals = *(const bf16x8*)(bufH + (kt * 64 + hi3 * 16 + rowst) * 8);
        } else {
          const float* src = q + (long)(cl * 16 + rowst) * 1024 + (ibase - 2048);
#pragma unroll
          for (int j = 0; j < 8; ++j) vals[j] = (short)f2bf(src[j]);
        }
        __syncthreads();
        *(bf16x8*)(catS + rowst * 128 + ioff) = vals;
        __syncthreads();
#pragma unroll
        for (int jj = 0; jj < 16; ++jj) {
          float wvv = mnet[(long)(ib * 128 + ig * 16 + jj) * 1024 + cg];
#pragma unroll
          for (int r2 = 0; r2 < 16; ++r2)
            acc[r2] += bf2f((unsigned short)catS[r2 * 128 + ig * 16 + jj]) * wvv;
        }
      }
      __syncthreads();
#pragma unroll
      for (int r2 = 0; r2 < 16; ++r2) accb[(ig * 16 + r2) * 32 + cc2] = acc[r2];
      __syncthreads();
#pragma unroll
      for (int k01 = 0; k01 < 2; ++k01) {
        int c = c0 + k01;
        int cg2 = w * 32 + c;
        float sum = 0.f;
#pragma unroll
        for (int ig2 = 0; ig2 < 8; ++ig2) sum += accb[(ig2 * 16 + r5) * 32 + c];
        float val = fmaxf(sum + mbias[cg2], 0.f);
        if (k01) h1 = val; else h0 = val;
        m0w[(long)browg * 1024 + cg2] = val;
        if (s == 2) out[(long)browg * 1024 + cg2] = val;
      }
      *(unsigned*)(bufP + pubOff) = (unsigned)f2bf(h0) | ((unsigned)f2bf(h1) << 16);
      ARRIVE();
    }
  }
}

// ---------------------------------------------------------------------------
extern "C" void kernel_launch(void* const* d_in, const int* in_sizes, int n_in,
                              void* d_out, int out_size, void* d_ws, size_t ws_size,
                              hipStream_t stream) {
  (void)in_sizes; (void)n_in; (void)out_size;
  if (ws_size < (size_t)WS_TOTAL) return;   // workspace too small -> fail loudly
  const float* facts = (const float*)d_in[0];
  const float* question = (const float*)d_in[1];
  // d_in[2..5] (l_1, bias_l1, l_2, bias_l2) are provably dead: softmax over axis of size 1.
  const float* rk = (const float*)d_in[6];
  const float* bias = (const float*)d_in[7];
  const float* mnet = (const float*)d_in[8];
  const float* mbias = (const float*)d_in[9];
  float* out = (float*)d_out;
  char* ws = (char*)d_ws;
  short* Xrh = (short*)(ws + WS_XRH);
  short* fb = (short*)(ws + WS_FB);
  short* Bt = (short*)(ws + WS_BT);
  short* pub = (short*)(ws + WS_PUB);
  unsigned* cnt = (unsigned*)(ws + WS_CNT);
  float* m0 = (float*)(ws + WS_M0);

  k_facts<<<dim3(16384), dim3(256), 0, stream>>>(facts, fb);
  k_trk<<<dim3(64, 32), dim3(32, 8), 0, stream>>>(rk, Bt);
  k_setup<<<dim3(256), dim3(256), 0, stream>>>(question, pub, cnt, m0);
  k_gemm<<<dim3(256, 16), dim3(256), 0, stream>>>(fb, Bt, bias, Xrh);
  k_scan<<<dim3(256), dim3(256), 0, stream>>>(Xrh, rk, question, mnet, mbias,
                                              pub, cnt, m0, out);
}

// Round 6
// 5152.108 us; speedup vs baseline: 5.0540x; 5.0540x over previous
//
#include <hip/hip_runtime.h>

// ---------------------------------------------------------------------------
// EpisodicMemoryModule, MI355X (gfx950).
// Softmax over a size-1 axis => attention == 1.0 => f_i / l_1 / l_2 are dead.
//   Xrh = facts @ recurrent_kernel + bias            (one bf16 MFMA GEMM)
//   3x { 256 sequential GRU steps; memory update }   (persistent kernel,
//        8 clusters x 32 wgs, weights in registers)
// R1 lesson: agent acquire/release fences = buffer_inv / buffer_wbl2 (full L2
// flush) per round -> 16.6us/round. Replace with sc1 (L2-bypass, MALL-coherent)
// data/flag traffic + vmcnt-ordered flag STORES (no atomic RMW, no fences).
// ---------------------------------------------------------------------------

using bf16x8 = __attribute__((ext_vector_type(8))) short;   // 8 bf16 (4 VGPRs)
using fx4    = __attribute__((ext_vector_type(4))) float;
using u32x4  = __attribute__((ext_vector_type(4))) unsigned;

__device__ __forceinline__ unsigned short f2bf(float f) {
  unsigned u = __float_as_uint(f);
  u += 0x7fffu + ((u >> 16) & 1u);          // RNE
  return (unsigned short)(u >> 16);
}
__device__ __forceinline__ float bf2f(unsigned short s) {
  return __uint_as_float(((unsigned)s) << 16);
}

#define MFMA16(a, b, c) __builtin_amdgcn_mfma_f32_16x16x32_bf16((a), (b), (c), 0, 0, 0)

// sc1 = agent-coherent: bypasses the (non-XCD-coherent) L2, served at MALL.
__device__ __forceinline__ bf16x8 ld16_sc(const short* p) {
  u32x4 t;
  asm volatile("global_load_dwordx4 %0, %1, off sc1" : "=v"(t) : "v"(p));
  return __builtin_bit_cast(bf16x8, t);
}
// After issuing ld16_sc's: drain + hard scheduling fence (rule #18: compiler
// may otherwise hoist register-only MFMAs above the waitcnt).
__device__ __forceinline__ void vm_drain() {
  asm volatile("s_waitcnt vmcnt(0)" ::: "memory");
  __builtin_amdgcn_sched_barrier(0);
}
__device__ __forceinline__ void st_u32_sc(unsigned* p, unsigned v) {
  __hip_atomic_store(p, v, __ATOMIC_RELAXED, __HIP_MEMORY_SCOPE_AGENT);
}
__device__ __forceinline__ unsigned ld_u32_sc(const unsigned* p) {
  return __hip_atomic_load(p, __ATOMIC_RELAXED, __HIP_MEMORY_SCOPE_AGENT);
}

// ---------------- workspace layout (bytes) ----------------
#define WS_XRH   0L                      // [32768][2048] bf16 (rows = n*128+b)
#define WS_FB    134217728L              // [32768][1024] bf16 facts, rows n*128+b
#define WS_BT    201326592L              // [2048][1024] bf16 = recurrent_kernel^T
#define WS_PUB   205520896L              // [2][8][16384] bf16 frag exchange
#define WS_CNT   206045184L              // [8][32][4] u32 per-wg round flags
#define WS_M0    206110720L              // [2][128][1024] f32 memory snapshots
#define WS_TOTAL 207159296L

// ---------------- facts f32 -> bf16, reindex rows to n*128+b ----------------
__global__ void k_facts(const float* __restrict__ facts, short* __restrict__ fb) {
  long i8 = ((long)blockIdx.x * 256 + threadIdx.x) * 8;
  if (i8 >= 33554432L) return;
  int u = (int)(i8 & 1023);
  int bn = (int)(i8 >> 10);       // output row = n*128 + b
  int b = bn & 127, n = bn >> 7;
  const float* src = facts + (((long)b * 256 + n) << 10) + u;
  bf16x8 o;
#pragma unroll
  for (int j = 0; j < 8; ++j) o[j] = (short)f2bf(src[j]);
  *(bf16x8*)(fb + i8) = o;
}

// ---------------- recurrent_kernel (1024,2048) f32 -> Bt (2048,1024) bf16 ----
__global__ void k_trk(const float* __restrict__ rk, short* __restrict__ bt) {
  __shared__ float tile[32][33];
  int j0 = blockIdx.x * 32, k0 = blockIdx.y * 32;
  int tx = threadIdx.x, ty = threadIdx.y;   // (32, 8)
#pragma unroll
  for (int yy = 0; yy < 4; ++yy) {
    int kk = ty + yy * 8;
    tile[kk][tx] = rk[(long)(k0 + kk) * 2048 + j0 + tx];
  }
  __syncthreads();
#pragma unroll
  for (int yy = 0; yy < 4; ++yy) {
    int jj = ty + yy * 8;
    bt[(long)(j0 + jj) * 1024 + k0 + tx] = (short)f2bf(tile[tx][jj]);
  }
}

// ---------------- setup: flags=0, q->h0 frags, m0[0]=q ----------------
__global__ void k_setup(const float* __restrict__ q, short* __restrict__ pub,
                        unsigned* __restrict__ cnt, float* __restrict__ m0) {
  int t = blockIdx.x * 256 + threadIdx.x;
  int stride = gridDim.x * 256;
  for (int i = t; i < 8 * 32 * 4; i += stride) cnt[i] = 0u;
  // publish q as A-fragments into pub[0]
  for (int i = t; i < 16384; i += stride) {
    int cl = i >> 11, u = i & 2047;
    int kt = u >> 6, ln = u & 63;
    int row = ln & 15, hi = ln >> 4;
    const float* src = q + (long)(cl * 16 + row) * 1024 + kt * 32 + hi * 8;
    bf16x8 o;
#pragma unroll
    for (int j = 0; j < 8; ++j) o[j] = (short)f2bf(src[j]);
    *(bf16x8*)(pub + (long)cl * 16384 + kt * 512 + ln * 8) = o;
  }
  for (int i = t; i < 32768; i += stride)
    ((float4*)m0)[i] = ((const float4*)q)[i];
}

// ---------------- Xrh GEMM: (32768,1024)bf16 @ (1024,2048)bf16 + bias -------
__global__ __launch_bounds__(256) void k_gemm(const short* __restrict__ A,
                                              const short* __restrict__ Bt,
                                              const float* __restrict__ bias,
                                              short* __restrict__ C) {
  __shared__ short As[128 * 40];
  __shared__ short Bs[128 * 40];
  const int tid = threadIdx.x, lane = tid & 63, wv = tid >> 6;
  const long bm = (long)blockIdx.x * 128;
  const long bn = (long)blockIdx.y * 128;
  fx4 acc[4][4];
#pragma unroll
  for (int m = 0; m < 4; ++m)
#pragma unroll
    for (int n = 0; n < 4; ++n) acc[m][n] = fx4{0.f, 0.f, 0.f, 0.f};
  const int r = tid >> 1, half = tid & 1;
  const short* aSrc = A + (bm + r) * 1024 + half * 16;
  const short* bSrc = Bt + (bn + r) * 1024 + half * 16;
  short* aDst = As + r * 40 + half * 16;
  short* bDst = Bs + r * 40 + half * 16;
  const int wm = (wv & 1) * 64, wn = (wv >> 1) * 64;
  for (int k0 = 0; k0 < 1024; k0 += 32) {
    bf16x8 a0 = *(const bf16x8*)(aSrc + k0);
    bf16x8 a1 = *(const bf16x8*)(aSrc + k0 + 8);
    bf16x8 b0 = *(const bf16x8*)(bSrc + k0);
    bf16x8 b1 = *(const bf16x8*)(bSrc + k0 + 8);
    *(bf16x8*)aDst = a0; *(bf16x8*)(aDst + 8) = a1;
    *(bf16x8*)bDst = b0; *(bf16x8*)(bDst + 8) = b1;
    __syncthreads();
    bf16x8 af[4], bfv[4];
#pragma unroll
    for (int m = 0; m < 4; ++m)
      af[m] = *(const bf16x8*)(As + (wm + m * 16 + (lane & 15)) * 40 + (lane >> 4) * 8);
#pragma unroll
    for (int n = 0; n < 4; ++n)
      bfv[n] = *(const bf16x8*)(Bs + (wn + n * 16 + (lane & 15)) * 40 + (lane >> 4) * 8);
#pragma unroll
    for (int m = 0; m < 4; ++m)
#pragma unroll
      for (int n = 0; n < 4; ++n) acc[m][n] = MFMA16(af[m], bfv[n], acc[m][n]);
    __syncthreads();
  }
#pragma unroll
  for (int n = 0; n < 4; ++n) {
    long colg = bn + wn + n * 16 + (lane & 15);
    float bv = bias[colg];
#pragma unroll
    for (int m = 0; m < 4; ++m) {
      long rowg = bm + wm + m * 16 + (lane >> 4) * 4;
#pragma unroll
      for (int rr = 0; rr < 4; ++rr)
        C[(rowg + rr) * 2048 + colg] = (short)f2bf(acc[m][n][rr] + bv);
    }
  }
}

// ---------------- persistent GRU scan + memory updates ----------------
// 256 wgs x 256 thr. cluster cl = blockIdx&7, slot w = blockIdx>>3 owns output
// cols [w*32, w*32+32). Flags: cnt[cl][w] = rounds produced by wg (monotonic).
// Round: poll flags >= R -> sc1 consume -> MFMA -> LDS reduce -> sc1 publish
// -> vmcnt(0) -> barrier -> flag store.

#define GATE()                                                                          \
  do {                                                                                  \
    const unsigned* fp = cntc + (lane & 31) * 4;                                        \
    while (!__all(ld_u32_sc(fp) >= (unsigned)R)) {}                                     \
    __builtin_amdgcn_sched_barrier(0);                                                  \
  } while (0)

#define ARRIVE()                                                                        \
  do {                                                                                  \
    vm_drain();                                                                         \
    __syncthreads();                                                                    \
    if (tid == 0) st_u32_sc(cntc + w * 4, (unsigned)(R + 1));                           \
    ++R;                                                                                \
  } while (0)

#define HALF_STEP(CONSUME, PRODUCE, BW, XV, IS_R)                                       \
  {                                                                                     \
    GATE();                                                                             \
    bf16x8 av[8];                                                                       \
    _Pragma("unroll") for (int kk = 0; kk < 8; ++kk)                                    \
        av[kk] = ld16_sc((CONSUME) + ((wv * 8 + kk) * 512 + lane * 8));                 \
    vm_drain();                                                                         \
    fx4 a0 = {0.f, 0.f, 0.f, 0.f}, a1 = {0.f, 0.f, 0.f, 0.f};                           \
    _Pragma("unroll") for (int kk = 0; kk < 8; ++kk) {                                  \
      a0 = MFMA16(av[kk], BW[kk][0], a0);                                               \
      a1 = MFMA16(av[kk], BW[kk][1], a1);                                               \
    }                                                                                   \
    _Pragma("unroll") for (int rr = 0; rr < 4; ++rr) {                                  \
      scratch[(wv * 2 + 0) * 256 + ((lane >> 4) * 4 + rr) * 16 + (lane & 15)] = a0[rr]; \
      scratch[(wv * 2 + 1) * 256 + ((lane >> 4) * 4 + rr) * 16 + (lane & 15)] = a1[rr]; \
    }                                                                                   \
    __syncthreads();                                                                    \
    {                                                                                   \
      int ct0 = c0 >> 4, cc0 = c0 & 15;                                                 \
      int ct1 = (c0 + 1) >> 4, cc1 = (c0 + 1) & 15;                                     \
      float s0 = scratch[ct0 * 256 + r5 * 16 + cc0] +                                   \
                 scratch[(2 + ct0) * 256 + r5 * 16 + cc0] +                             \
                 scratch[(4 + ct0) * 256 + r5 * 16 + cc0] +                             \
                 scratch[(6 + ct0) * 256 + r5 * 16 + cc0];                              \
      float s1 = scratch[ct1 * 256 + r5 * 16 + cc1] +                                   \
                 scratch[(2 + ct1) * 256 + r5 * 16 + cc1] +                             \
                 scratch[(4 + ct1) * 256 + r5 * 16 + cc1] +                             \
                 scratch[(6 + ct1) * 256 + r5 * 16 + cc1];                              \
      float p0 = s0 + bf2f((unsigned short)((XV) & 0xffffu));                           \
      float p1 = s1 + bf2f((unsigned short)((XV) >> 16));                               \
      float v0, v1;                                                                     \
      if (IS_R) {                                                                       \
        float r0 = fminf(fmaxf(0.2f * p0 + 0.5f, 0.f), 1.f);                            \
        float r1 = fminf(fmaxf(0.2f * p1 + 0.5f, 0.f), 1.f);                            \
        v0 = r0 * h0; v1 = r1 * h1;                                                     \
      } else {                                                                          \
        v0 = 1.f / (1.f + __expf(-p0));                                                 \
        v1 = 1.f / (1.f + __expf(-p1));                                                 \
        h0 = v0; h1 = v1;                                                               \
      }                                                                                 \
      st_u32_sc((unsigned*)((PRODUCE) + pubOff),                                        \
                (unsigned)f2bf(v0) | ((unsigned)f2bf(v1) << 16));                       \
    }                                                                                   \
    ARRIVE();                                                                           \
  }

__global__ __launch_bounds__(256, 1) void k_scan(
    const short* __restrict__ Xrh, const float* __restrict__ rk,
    const float* __restrict__ q, const float* __restrict__ mnet,
    const float* __restrict__ mbias, short* __restrict__ pub,
    unsigned* __restrict__ cnt, float* __restrict__ m0, float* __restrict__ out) {
  __shared__ short wstage[4096];     // 8 KB weight-frag bounce
  __shared__ float scratch[5120];    // 20 KB: scan partials / update cat+acc
  const int tid = threadIdx.x;
  const int lane = tid & 63, wv = tid >> 6;
  const int g = blockIdx.x, cl = g & 7, w = g >> 3;

  // ---- weight B-fragments into registers (wave wv owns k-tiles wv*8..wv*8+7)
  bf16x8 bfrR[8][2], bfrH[8][2];
#pragma unroll
  for (int kind = 0; kind < 2; ++kind) {
#pragma unroll
    for (int ch = 0; ch < 8; ++ch) {
      for (int it = 0; it < 16; ++it) {   // stage 128 k-rows x 32 cols
        int idx = it * 256 + tid;
        int kl = idx >> 5, cc = idx & 31;
        float v = rk[(long)(ch * 128 + kl) * 2048 + kind * 1024 + w * 32 + cc];
        int kt4 = kl >> 5, kr = kl & 31;
        int hi2 = kr >> 3, j = kr & 7;
        int ct = cc >> 4, l15 = cc & 15;
        wstage[((kt4 * 2 + ct) * 64 + (hi2 * 16 + l15)) * 8 + j] = (short)f2bf(v);
      }
      __syncthreads();
      if (wv == (ch >> 1)) {
#pragma unroll
        for (int kt4 = 0; kt4 < 4; ++kt4)
#pragma unroll
          for (int ct = 0; ct < 2; ++ct) {
            bf16x8 fr = *(const bf16x8*)&wstage[((kt4 * 2 + ct) * 64 + lane) * 8];
            if (kind == 0) bfrR[(ch & 1) * 4 + kt4][ct] = fr;
            else           bfrH[(ch & 1) * 4 + kt4][ct] = fr;
          }
      }
      __syncthreads();
    }
  }

  // ---- per-thread output mapping: (row r5, cols c0,c0+1) of this wg's slice
  const int r5 = (tid >> 2) & 15, q2 = tid & 3;
  const int c0 = wv * 8 + q2 * 2;
  const int browg = cl * 16 + r5;
  float h0 = q[(long)browg * 1024 + w * 32 + c0];
  float h1 = q[(long)browg * 1024 + w * 32 + c0 + 1];
  unsigned* cntc = cnt + cl * 128;              // [32 slots][4]
  const int pubOff = w * 512 + (wv * 16 + r5) * 8 + q2 * 2;
  const long clOff = (long)cl * 16384;
  int R = 0;                                    // rounds produced by this wg

  for (int s = 0; s < 3; ++s) {
    const int pin = s & 1;
    short* bufH = pub + (long)pin * 131072 + clOff;
    short* bufP = pub + (long)(pin ^ 1) * 131072 + clOff;
    for (int n = 0; n < 256; ++n) {
      const long xrow = ((long)n * 128 + browg) * 2048;
      unsigned xvR = *(const unsigned*)(Xrh + xrow + w * 32 + c0);
      unsigned xvH = *(const unsigned*)(Xrh + xrow + 1024 + w * 32 + c0);
      HALF_STEP(bufH, bufP, bfrR, xvR, 1)          // r = hsig(Xr + h@k_r); p=r*h
      HALF_STEP(bufP, bufH, bfrH, xvH, 0)          // h' = sig(Xh + p@k_h)
    }
    // ---------- memory update: relu([m0, episode, q] @ mnet + mbias) ----------
    {
      const float* m0r = m0 + (long)(s & 1) * 131072;
      float* m0w = m0 + (long)((s + 1) & 1) * 131072;
      GATE();
      short* catS = (short*)scratch;     // [16][128] bf16
      float* accb = scratch + 1024;      // [8][16][32] f32
      float acc[16];
#pragma unroll
      for (int r2 = 0; r2 < 16; ++r2) acc[r2] = 0.f;
      const int cc2 = tid & 31, ig = tid >> 5;
      const int cg = w * 32 + cc2;
      const int rowst = tid >> 4, ioff = (tid & 15) * 8;
      for (int ib = 0; ib < 24; ++ib) {
        int ibase = ib * 128 + ioff;
        bf16x8 vals;
        if (ib < 8) {
          const unsigned* src =
              (const unsigned*)(m0r + (long)(cl * 16 + rowst) * 1024 + ibase);
#pragma unroll
          for (int j = 0; j < 8; ++j)
            vals[j] = (short)f2bf(__uint_as_float(ld_u32_sc(src + j)));
        } else if (ib < 16) {
          int col8 = ibase - 1024;
          int kt = col8 >> 5, hi3 = (col8 >> 3) & 3;
          vals = ld16_sc(bufH + (kt * 64 + hi3 * 16 + rowst) * 8);
          vm_drain();
        } else {
          const float* src = q + (long)(cl * 16 + rowst) * 1024 + (ibase - 2048);
#pragma unroll
          for (int j = 0; j < 8; ++j) vals[j] = (short)f2bf(src[j]);
        }
        __syncthreads();
        *(bf16x8*)(catS + rowst * 128 + ioff) = vals;
        __syncthreads();
#pragma unroll
        for (int jj = 0; jj < 16; ++jj) {
          float wvv = mnet[(long)(ib * 128 + ig * 16 + jj) * 1024 + cg];
#pragma unroll
          for (int r2 = 0; r2 < 16; ++r2)
            acc[r2] += bf2f((unsigned short)catS[r2 * 128 + ig * 16 + jj]) * wvv;
        }
      }
      __syncthreads();
#pragma unroll
      for (int r2 = 0; r2 < 16; ++r2) accb[(ig * 16 + r2) * 32 + cc2] = acc[r2];
      __syncthreads();
#pragma unroll
      for (int k01 = 0; k01 < 2; ++k01) {
        int c = c0 + k01;
        int cg2 = w * 32 + c;
        float sum = 0.f;
#pragma unroll
        for (int ig2 = 0; ig2 < 8; ++ig2) sum += accb[(ig2 * 16 + r5) * 32 + c];
        float val = fmaxf(sum + mbias[cg2], 0.f);
        if (k01) h1 = val; else h0 = val;
        st_u32_sc((unsigned*)(m0w + (long)browg * 1024 + cg2), __float_as_uint(val));
        if (s == 2) out[(long)browg * 1024 + cg2] = val;
      }
      st_u32_sc((unsigned*)(bufP + pubOff),
                (unsigned)f2bf(h0) | ((unsigned)f2bf(h1) << 16));
      ARRIVE();
    }
  }
}

// ---------------------------------------------------------------------------
extern "C" void kernel_launch(void* const* d_in, const int* in_sizes, int n_in,
                              void* d_out, int out_size, void* d_ws, size_t ws_size,
                              hipStream_t stream) {
  (void)in_sizes; (void)n_in; (void)out_size;
  if (ws_size < (size_t)WS_TOTAL) return;
  const float* facts = (const float*)d_in[0];
  const float* question = (const float*)d_in[1];
  // d_in[2..5] (l_1, bias_l1, l_2, bias_l2) are dead: softmax over size-1 axis.
  const float* rk = (const float*)d_in[6];
  const float* bias = (const float*)d_in[7];
  const float* mnet = (const float*)d_in[8];
  const float* mbias = (const float*)d_in[9];
  float* out = (float*)d_out;
  char* ws = (char*)d_ws;
  short* Xrh = (short*)(ws + WS_XRH);
  short* fb = (short*)(ws + WS_FB);
  short* Bt = (short*)(ws + WS_BT);
  short* pub = (short*)(ws + WS_PUB);
  unsigned* cnt = (unsigned*)(ws + WS_CNT);
  float* m0 = (float*)(ws + WS_M0);

  k_facts<<<dim3(16384), dim3(256), 0, stream>>>(facts, fb);
  k_trk<<<dim3(64, 32), dim3(32, 8), 0, stream>>>(rk, Bt);
  k_setup<<<dim3(256), dim3(256), 0, stream>>>(question, pub, cnt, m0);
  k_gemm<<<dim3(256, 16), dim3(256), 0, stream>>>(fb, Bt, bias, Xrh);
  k_scan<<<dim3(256), dim3(256), 0, stream>>>(Xrh, rk, question, mnet, mbias,
                                              pub, cnt, m0, out);
}